// Round 1
// baseline (7132.536 us; speedup 1.0000x reference)
//
#include <hip/hip_runtime.h>
#include <math.h>

#define C 16
#define FIN 128

__global__ __launch_bounds__(256) void k_deg_loop(
    const int* __restrict__ dst, const float2* __restrict__ ea,
    float* __restrict__ deg, float* __restrict__ loop_sum, int ne) {
  int e = blockIdx.x * 256 + threadIdx.x;
  if (e >= ne) return;
  int d = dst[e];
  float2 a = ea[e];
  atomicAdd(&deg[d], 1.0f);
  atomicAdd(&loop_sum[2 * d], a.x);
  atomicAdd(&loop_sum[2 * d + 1], a.y);
}

__global__ __launch_bounds__(256) void k_gemm1(
    const float* __restrict__ x, const float* __restrict__ W,
    float* __restrict__ h, int n) {
  __shared__ float xs[64 * 129];   // +1 pad: bank = (n + k) % 32, 2-way -> free
  __shared__ float Ws[FIN * C];
  int t = threadIdx.x;
  int node0 = blockIdx.x * 64;
  for (int i = t; i < FIN * C; i += 256) Ws[i] = W[i];
  for (int i = t; i < 64 * FIN; i += 256) {
    int r = i >> 7, c = i & 127;
    int node = node0 + r;
    xs[r * 129 + c] = (node < n) ? x[(size_t)node * FIN + c] : 0.f;
  }
  __syncthreads();
  int nn = t & 63, cg = (t >> 6) * 4;
  float a0 = 0.f, a1 = 0.f, a2 = 0.f, a3 = 0.f;
  const float* xr = &xs[nn * 129];
  #pragma unroll 8
  for (int k = 0; k < FIN; ++k) {
    float xv = xr[k];
    const float* wr = &Ws[k * C + cg];
    a0 += xv * wr[0]; a1 += xv * wr[1]; a2 += xv * wr[2]; a3 += xv * wr[3];
  }
  int node = node0 + nn;
  if (node < n) {
    float4* outp = (float4*)&h[(size_t)node * C + cg];
    *outp = make_float4(a0, a1, a2, a3);
  }
}

__global__ __launch_bounds__(256) void k_node1(
    const float* __restrict__ h, const float* __restrict__ deg,
    const float* __restrict__ loop_sum,
    const float* __restrict__ We, const float* __restrict__ aew,
    const float* __restrict__ asw, const float* __restrict__ adw,
    float* __restrict__ a_s, float* __restrict__ a_d,
    float* __restrict__ denom, float* __restrict__ agg, int n) {
  int i = blockIdx.x * 256 + threadIdx.x;
  if (i >= n) return;
  float we0 = 0.f, we1 = 0.f;
  #pragma unroll
  for (int c = 0; c < C; ++c) { we0 += We[c] * aew[c]; we1 += We[C + c] * aew[c]; }
  float hr[C];
  #pragma unroll
  for (int c = 0; c < C; ++c) hr[c] = h[(size_t)i * C + c];
  float hs = 0.f, hd = 0.f;
  #pragma unroll
  for (int c = 0; c < C; ++c) { hs += hr[c] * asw[c]; hd += hr[c] * adw[c]; }
  a_s[i] = hs; a_d[i] = hd;
  float dgc = fmaxf(deg[i], 1.f);
  float lg = hs + hd + (loop_sum[2 * i] * we0 + loop_sum[2 * i + 1] * we1) / dgc;
  lg = lg > 0.f ? lg : 0.2f * lg;
  float ex = expf(lg);
  denom[i] = ex;
  #pragma unroll
  for (int c = 0; c < C; ++c) agg[(size_t)i * C + c] = ex * hr[c];
}

__global__ __launch_bounds__(256) void k_edge(
    const int* __restrict__ src, const int* __restrict__ dst,
    const float2* __restrict__ ea,
    const float* __restrict__ a_s, const float* __restrict__ a_d,
    const float* __restrict__ h,
    const float* __restrict__ We, const float* __restrict__ aew,
    float* __restrict__ denom, float* __restrict__ agg, int ne) {
  int e = blockIdx.x * 256 + threadIdx.x;
  if (e >= ne) return;
  float we0 = 0.f, we1 = 0.f;
  #pragma unroll
  for (int c = 0; c < C; ++c) { we0 += We[c] * aew[c]; we1 += We[C + c] * aew[c]; }
  int s = src[e], d = dst[e];
  float2 a = ea[e];
  float lg = a_s[s] + a_d[d] + a.x * we0 + a.y * we1;
  lg = lg > 0.f ? lg : 0.2f * lg;
  float ex = expf(lg);
  atomicAdd(&denom[d], ex);
  const float* hsrc = &h[(size_t)s * C];
  #pragma unroll
  for (int c = 0; c < C; ++c) atomicAdd(&agg[(size_t)d * C + c], ex * hsrc[c]);
}

__global__ __launch_bounds__(256) void k_fin1(
    float* __restrict__ agg, const float* __restrict__ denom,
    const float* __restrict__ b,
    float* __restrict__ bnsum, float* __restrict__ bnsq, int n) {
  int i = blockIdx.x * 256 + threadIdx.x;
  float v[C];
  if (i < n) {
    float inv = 1.f / denom[i];
    #pragma unroll
    for (int c = 0; c < C; ++c) {
      float t = fmaxf(agg[(size_t)i * C + c] * inv + b[c], 0.f);
      v[c] = t; agg[(size_t)i * C + c] = t;
    }
  } else {
    #pragma unroll
    for (int c = 0; c < C; ++c) v[c] = 0.f;
  }
  #pragma unroll
  for (int c = 0; c < C; ++c) {
    float s = v[c], q = v[c] * v[c];
    for (int o = 32; o > 0; o >>= 1) { s += __shfl_down(s, o); q += __shfl_down(q, o); }
    if ((threadIdx.x & 63) == 0) { atomicAdd(&bnsum[c], s); atomicAdd(&bnsq[c], q); }
  }
}

__global__ void k_bnp(const float* __restrict__ bnsum, const float* __restrict__ bnsq,
                      const float* __restrict__ g, const float* __restrict__ bb,
                      float* __restrict__ scale, float* __restrict__ shift, float invn) {
  int c = threadIdx.x;
  if (c >= C) return;
  float mean = bnsum[c] * invn;
  float var = bnsq[c] * invn - mean * mean;
  float s = g[c] * rsqrtf(var + 1e-5f);
  scale[c] = s; shift[c] = bb[c] - mean * s;
}

__global__ __launch_bounds__(256) void k_node2(
    float* __restrict__ agg, float* __restrict__ h,
    const float* __restrict__ scale, const float* __restrict__ shift,
    const float* __restrict__ W2,
    const float* __restrict__ We, const float* __restrict__ aew,
    const float* __restrict__ asw, const float* __restrict__ adw,
    const float* __restrict__ deg, const float* __restrict__ loop_sum,
    float* __restrict__ a_s, float* __restrict__ a_d,
    float* __restrict__ denom, int n) {
  int i = blockIdx.x * 256 + threadIdx.x;
  if (i >= n) return;
  float we0 = 0.f, we1 = 0.f;
  #pragma unroll
  for (int c = 0; c < C; ++c) { we0 += We[c] * aew[c]; we1 += We[C + c] * aew[c]; }
  float hn[C];
  #pragma unroll
  for (int c = 0; c < C; ++c) hn[c] = agg[(size_t)i * C + c] * scale[c] + shift[c];
  float h2[C];
  #pragma unroll
  for (int j = 0; j < C; ++j) {
    float acc = 0.f;
    #pragma unroll
    for (int c = 0; c < C; ++c) acc += hn[c] * W2[c * C + j];
    h2[j] = acc;
  }
  float hs = 0.f, hd = 0.f;
  #pragma unroll
  for (int j = 0; j < C; ++j) { hs += h2[j] * asw[j]; hd += h2[j] * adw[j]; h[(size_t)i * C + j] = h2[j]; }
  a_s[i] = hs; a_d[i] = hd;
  float dgc = fmaxf(deg[i], 1.f);
  float lg = hs + hd + (loop_sum[2 * i] * we0 + loop_sum[2 * i + 1] * we1) / dgc;
  lg = lg > 0.f ? lg : 0.2f * lg;
  float ex = expf(lg);
  denom[i] = ex;
  #pragma unroll
  for (int j = 0; j < C; ++j) agg[(size_t)i * C + j] = ex * h2[j];
}

__global__ __launch_bounds__(256) void k_fin2(
    const float* __restrict__ agg, const float* __restrict__ denom,
    const float* __restrict__ b, const int* __restrict__ batch,
    float* __restrict__ xe_sum, float* __restrict__ cnt, int n) {
  int i = blockIdx.x * 256 + threadIdx.x;
  if (i >= n) return;
  float inv = 1.f / denom[i];
  int g = batch[i];
  atomicAdd(&cnt[g], 1.f);
  #pragma unroll
  for (int c = 0; c < C; ++c) {
    float t = fmaxf(agg[(size_t)i * C + c] * inv + b[c], 0.f);
    atomicAdd(&xe_sum[g * C + c], t);
  }
}

__device__ __forceinline__ void head64(const float* z, const float* __restrict__ W,
                                       const float* __restrict__ b, float* __restrict__ o) {
  float l[64]; float mx = -1e30f;
  #pragma unroll
  for (int j = 0; j < 64; ++j) {
    float acc = b[j];
    #pragma unroll
    for (int c = 0; c < C; ++c) acc += z[c] * W[c * 64 + j];
    l[j] = acc; mx = fmaxf(mx, acc);
  }
  float ssum = 0.f;
  #pragma unroll
  for (int j = 0; j < 64; ++j) { l[j] = expf(l[j] - mx); ssum += l[j]; }
  float inv = 1.f / ssum;
  #pragma unroll
  for (int j = 0; j < 64; ++j) o[j] = l[j] * inv;
}

__global__ __launch_bounds__(512) void k_tail(
    const float* __restrict__ xe_sum, const float* __restrict__ cnt,
    const float* __restrict__ gL1, const float* __restrict__ bL1,
    const float* __restrict__ Wl1, const float* __restrict__ bl1,
    const float* __restrict__ gL2, const float* __restrict__ bL2,
    const float* __restrict__ Wl2, const float* __restrict__ bl2,
    const float* __restrict__ gL3, const float* __restrict__ bL3,
    const float* __restrict__ Wl3, const float* __restrict__ bl3,
    const float* __restrict__ Wx, const float* __restrict__ bx,
    const float* __restrict__ Wy, const float* __restrict__ by,
    const float* __restrict__ Wr, const float* __restrict__ br,
    float* __restrict__ out, int B_) {
  __shared__ float ssum[2 * C], ssq[2 * C], sc[2 * C], sh[2 * C];
  int t = threadIdx.x;
  float invB = 1.f / (float)B_;
  float xe[C];
  float cn = fmaxf(cnt[t], 1.f);
  #pragma unroll
  for (int c = 0; c < C; ++c) xe[c] = xe_sum[t * C + c] / cn;

  // ---- BN1 over 16 channels of xe ----
  if (t < 2 * C) { ssum[t] = 0.f; ssq[t] = 0.f; }
  __syncthreads();
  #pragma unroll
  for (int c = 0; c < C; ++c) {
    float s = xe[c], q = xe[c] * xe[c];
    for (int o = 32; o > 0; o >>= 1) { s += __shfl_down(s, o); q += __shfl_down(q, o); }
    if ((t & 63) == 0) { atomicAdd(&ssum[c], s); atomicAdd(&ssq[c], q); }
  }
  __syncthreads();
  if (t < C) {
    float mean = ssum[t] * invB, var = ssq[t] * invB - mean * mean;
    float s = gL1[t] * rsqrtf(var + 1e-5f);
    sc[t] = s; sh[t] = bL1[t] - mean * s;
  }
  __syncthreads();
  float z[C];
  #pragma unroll
  for (int j = 0; j < C; ++j) {
    float acc = bl1[j];
    #pragma unroll
    for (int c = 0; c < C; ++c) acc += (xe[c] * sc[c] + sh[c]) * Wl1[c * C + j];
    z[j] = fmaxf(acc, 0.f);
  }
  __syncthreads();

  // ---- BN2 over 32 channels [z, xe] ----
  if (t < 2 * C) { ssum[t] = 0.f; ssq[t] = 0.f; }
  __syncthreads();
  #pragma unroll
  for (int c = 0; c < C; ++c) {
    float s = z[c], q = z[c] * z[c];
    for (int o = 32; o > 0; o >>= 1) { s += __shfl_down(s, o); q += __shfl_down(q, o); }
    if ((t & 63) == 0) { atomicAdd(&ssum[c], s); atomicAdd(&ssq[c], q); }
    float s2 = xe[c], q2 = xe[c] * xe[c];
    for (int o = 32; o > 0; o >>= 1) { s2 += __shfl_down(s2, o); q2 += __shfl_down(q2, o); }
    if ((t & 63) == 0) { atomicAdd(&ssum[C + c], s2); atomicAdd(&ssq[C + c], q2); }
  }
  __syncthreads();
  if (t < 2 * C) {
    float mean = ssum[t] * invB, var = ssq[t] * invB - mean * mean;
    float s = gL2[t] * rsqrtf(var + 1e-5f);
    sc[t] = s; sh[t] = bL2[t] - mean * s;
  }
  __syncthreads();
  float z2[C];
  #pragma unroll
  for (int j = 0; j < C; ++j) {
    float acc = bl2[j];
    #pragma unroll
    for (int c = 0; c < C; ++c) acc += (z[c] * sc[c] + sh[c]) * Wl2[c * C + j];
    #pragma unroll
    for (int c = 0; c < C; ++c) acc += (xe[c] * sc[C + c] + sh[C + c]) * Wl2[(C + c) * C + j];
    z2[j] = fmaxf(acc, 0.f);
  }
  __syncthreads();

  // ---- BN3 over 32 channels [z2, xe] ----
  if (t < 2 * C) { ssum[t] = 0.f; ssq[t] = 0.f; }
  __syncthreads();
  #pragma unroll
  for (int c = 0; c < C; ++c) {
    float s = z2[c], q = z2[c] * z2[c];
    for (int o = 32; o > 0; o >>= 1) { s += __shfl_down(s, o); q += __shfl_down(q, o); }
    if ((t & 63) == 0) { atomicAdd(&ssum[c], s); atomicAdd(&ssq[c], q); }
    float s2 = xe[c], q2 = xe[c] * xe[c];
    for (int o = 32; o > 0; o >>= 1) { s2 += __shfl_down(s2, o); q2 += __shfl_down(q2, o); }
    if ((t & 63) == 0) { atomicAdd(&ssum[C + c], s2); atomicAdd(&ssq[C + c], q2); }
  }
  __syncthreads();
  if (t < 2 * C) {
    float mean = ssum[t] * invB, var = ssq[t] * invB - mean * mean;
    float s = gL3[t] * rsqrtf(var + 1e-5f);
    sc[t] = s; sh[t] = bL3[t] - mean * s;
  }
  __syncthreads();
  float z3[C];
  #pragma unroll
  for (int j = 0; j < C; ++j) {
    float acc = bl3[j];
    #pragma unroll
    for (int c = 0; c < C; ++c) acc += (z2[c] * sc[c] + sh[c]) * Wl3[c * C + j];
    #pragma unroll
    for (int c = 0; c < C; ++c) acc += (xe[c] * sc[C + c] + sh[C + c]) * Wl3[(C + c) * C + j];
    z3[j] = fmaxf(acc, 0.f);
  }

  // ---- heads ----
  head64(z3, Wx, bx, out + (size_t)t * 64);
  head64(z3, Wy, by, out + (size_t)B_ * 64 + (size_t)t * 64);
  float r[4]; float mx = -1e30f;
  #pragma unroll
  for (int j = 0; j < 4; ++j) {
    float acc = br[j];
    #pragma unroll
    for (int c = 0; c < C; ++c) acc += z3[c] * Wr[c * 4 + j];
    r[j] = acc; mx = fmaxf(mx, acc);
  }
  float ssm = 0.f;
  #pragma unroll
  for (int j = 0; j < 4; ++j) { r[j] = expf(r[j] - mx); ssm += r[j]; }
  #pragma unroll
  for (int j = 0; j < 4; ++j) out[(size_t)B_ * 128 + (size_t)t * 4 + j] = r[j] / ssm;
}

extern "C" void kernel_launch(void* const* d_in, const int* in_sizes, int n_in,
                              void* d_out, int out_size, void* d_ws, size_t ws_size,
                              hipStream_t stream) {
  const float* x     = (const float*)d_in[0];
  const int*   eidx  = (const int*)d_in[1];
  const float* eattr = (const float*)d_in[2];
  const int*   batch = (const int*)d_in[3];
  const float* W1  = (const float*)d_in[4];
  const float* We1 = (const float*)d_in[5];
  const float* as1 = (const float*)d_in[6];
  const float* ad1 = (const float*)d_in[7];
  const float* ae1 = (const float*)d_in[8];
  const float* b1  = (const float*)d_in[9];
  const float* g1  = (const float*)d_in[10];
  const float* bb1 = (const float*)d_in[11];
  const float* W2  = (const float*)d_in[12];
  const float* We2 = (const float*)d_in[13];
  const float* as2 = (const float*)d_in[14];
  const float* ad2 = (const float*)d_in[15];
  const float* ae2 = (const float*)d_in[16];
  const float* b2  = (const float*)d_in[17];
  const float* gL1 = (const float*)d_in[18];
  const float* bL1 = (const float*)d_in[19];
  const float* Wl1 = (const float*)d_in[20];
  const float* bl1 = (const float*)d_in[21];
  const float* gL2 = (const float*)d_in[22];
  const float* bL2 = (const float*)d_in[23];
  const float* Wl2 = (const float*)d_in[24];
  const float* bl2 = (const float*)d_in[25];
  const float* gL3 = (const float*)d_in[26];
  const float* bL3 = (const float*)d_in[27];
  const float* Wl3 = (const float*)d_in[28];
  const float* bl3 = (const float*)d_in[29];
  const float* Wx  = (const float*)d_in[30];
  const float* bx  = (const float*)d_in[31];
  const float* Wy  = (const float*)d_in[32];
  const float* by  = (const float*)d_in[33];
  const float* Wr  = (const float*)d_in[34];
  const float* br  = (const float*)d_in[35];

  int N = in_sizes[3];
  int E = in_sizes[2] / 2;
  int B = out_size / 132;

  float* w = (float*)d_ws;
  size_t o = 0;
  float* deg      = w + o; o += (size_t)N;
  float* loop_sum = w + o; o += 2 * (size_t)N;
  float* h        = w + o; o += 16 * (size_t)N;
  float* a_s      = w + o; o += (size_t)N;
  float* a_d      = w + o; o += (size_t)N;
  float* denom    = w + o; o += (size_t)N;
  float* agg      = w + o; o += 16 * (size_t)N;
  float* bnsum    = w + o; o += 16;
  float* bnsq     = w + o; o += 16;
  float* scale    = w + o; o += 16;
  float* shift    = w + o; o += 16;
  float* xe_sum   = w + o; o += (size_t)B * 16;
  float* cnt      = w + o; o += (size_t)B;

  hipMemsetAsync(deg, 0, (size_t)3 * N * sizeof(float), stream);          // deg + loop_sum
  hipMemsetAsync(bnsum, 0, 32 * sizeof(float), stream);                   // bnsum + bnsq
  hipMemsetAsync(xe_sum, 0, (size_t)B * 17 * sizeof(float), stream);      // xe_sum + cnt

  const int* src = eidx;
  const int* dst = eidx + E;
  int ebl = (E + 255) / 256, nbl = (N + 255) / 256;

  k_deg_loop<<<ebl, 256, 0, stream>>>(dst, (const float2*)eattr, deg, loop_sum, E);
  k_gemm1<<<(N + 63) / 64, 256, 0, stream>>>(x, W1, h, N);
  k_node1<<<nbl, 256, 0, stream>>>(h, deg, loop_sum, We1, ae1, as1, ad1, a_s, a_d, denom, agg, N);
  k_edge<<<ebl, 256, 0, stream>>>(src, dst, (const float2*)eattr, a_s, a_d, h, We1, ae1, denom, agg, E);
  k_fin1<<<nbl, 256, 0, stream>>>(agg, denom, b1, bnsum, bnsq, N);
  k_bnp<<<1, 64, 0, stream>>>(bnsum, bnsq, g1, bb1, scale, shift, 1.f / (float)N);
  k_node2<<<nbl, 256, 0, stream>>>(agg, h, scale, shift, W2, We2, ae2, as2, ad2, deg, loop_sum, a_s, a_d, denom, N);
  k_edge<<<ebl, 256, 0, stream>>>(src, dst, (const float2*)eattr, a_s, a_d, h, We2, ae2, denom, agg, E);
  k_fin2<<<nbl, 256, 0, stream>>>(agg, denom, b2, batch, xe_sum, cnt, N);
  k_tail<<<1, B, 0, stream>>>(xe_sum, cnt, gL1, bL1, Wl1, bl1, gL2, bL2, Wl2, bl2,
                              gL3, bL3, Wl3, bl3, Wx, bx, Wy, by, Wr, br, (float*)d_out, B);
}

// Round 2
// 1268.780 us; speedup vs baseline: 5.6216x; 5.6216x over previous
//
#include <hip/hip_runtime.h>
#include <hip/hip_fp16.h>
#include <math.h>

#define C 16
#define FIN 128

// ---------------- GEMM x@W1 (100k x 128 x 16) + fused a_s/a_d ----------------
__global__ __launch_bounds__(256) void k_gemm1(
    const float* __restrict__ x, const float* __restrict__ W,
    const float* __restrict__ asw, const float* __restrict__ adw,
    float* __restrict__ h, float* __restrict__ a_s, float* __restrict__ a_d, int n) {
  __shared__ float xs[64 * 129];
  __shared__ float Ws[FIN * C];
  __shared__ float pAs[4][64], pAd[4][64];
  int t = threadIdx.x;
  int node0 = blockIdx.x * 64;
  for (int i = t; i < FIN * C; i += 256) Ws[i] = W[i];
  for (int i = t; i < 64 * FIN; i += 256) {
    int r = i >> 7, c = i & 127;
    int node = node0 + r;
    xs[r * 129 + c] = (node < n) ? x[(size_t)node * FIN + c] : 0.f;
  }
  __syncthreads();
  int nn = t & 63, cg = (t >> 6) * 4, grp = t >> 6;
  float a0 = 0.f, a1 = 0.f, a2 = 0.f, a3 = 0.f;
  const float* xr = &xs[nn * 129];
  #pragma unroll 8
  for (int k = 0; k < FIN; ++k) {
    float xv = xr[k];
    const float* wr = &Ws[k * C + cg];
    a0 += xv * wr[0]; a1 += xv * wr[1]; a2 += xv * wr[2]; a3 += xv * wr[3];
  }
  int node = node0 + nn;
  if (node < n) {
    float4* outp = (float4*)&h[(size_t)node * C + cg];
    *outp = make_float4(a0, a1, a2, a3);
  }
  pAs[grp][nn] = a0 * asw[cg] + a1 * asw[cg + 1] + a2 * asw[cg + 2] + a3 * asw[cg + 3];
  pAd[grp][nn] = a0 * adw[cg] + a1 * adw[cg + 1] + a2 * adw[cg + 2] + a3 * adw[cg + 3];
  __syncthreads();
  if (t < 64 && node0 + t < n) {
    a_s[node0 + t] = pAs[0][t] + pAs[1][t] + pAs[2][t] + pAs[3][t];
    a_d[node0 + t] = pAd[0][t] + pAd[1][t] + pAd[2][t] + pAd[3][t];
  }
}

// ---------------- CSR build ----------------
__global__ __launch_bounds__(256) void k_hist(const int* __restrict__ dst,
                                              int* __restrict__ counts, int ne) {
  int e = blockIdx.x * 256 + threadIdx.x;
  if (e < ne) atomicAdd(&counts[dst[e]], 1);
}

__global__ __launch_bounds__(512) void k_scan1(const int* __restrict__ counts,
                                               int* __restrict__ bsum, int n) {
  __shared__ int sd[512];
  int i = blockIdx.x * 512 + threadIdx.x;
  sd[threadIdx.x] = (i < n) ? counts[i] : 0;
  __syncthreads();
  for (int s = 256; s > 0; s >>= 1) {
    if (threadIdx.x < s) sd[threadIdx.x] += sd[threadIdx.x + s];
    __syncthreads();
  }
  if (threadIdx.x == 0) bsum[blockIdx.x] = sd[0];
}

__global__ void k_scan2(int* __restrict__ bsum, int* __restrict__ offs,
                        int nblk, int n) {
  int run = 0;
  for (int b = 0; b < nblk; ++b) { int t = bsum[b]; bsum[b] = run; run += t; }
  offs[n] = run;
}

__global__ __launch_bounds__(512) void k_scan3(const int* __restrict__ counts,
                                               const int* __restrict__ bsum,
                                               int* __restrict__ offs, int n) {
  __shared__ int sd[512];
  int t = threadIdx.x;
  int i = blockIdx.x * 512 + t;
  int v = (i < n) ? counts[i] : 0;
  sd[t] = v;
  __syncthreads();
  for (int off = 1; off < 512; off <<= 1) {
    int x = (t >= off) ? sd[t - off] : 0;
    __syncthreads();
    sd[t] += x;
    __syncthreads();
  }
  if (i < n) offs[i] = bsum[blockIdx.x] + sd[t] - v;
}

__global__ __launch_bounds__(256) void k_scatter(
    const int* __restrict__ src, const int* __restrict__ dst,
    const float2* __restrict__ ea, const int* __restrict__ offs,
    int* __restrict__ cursor, uint2* __restrict__ bucket, int ne) {
  int e = blockIdx.x * 256 + threadIdx.x;
  if (e >= ne) return;
  int d = dst[e];
  int pos = atomicAdd(&cursor[d], 1);
  float2 a = ea[e];
  __half2 hh = __floats2half2_rn(a.x, a.y);
  unsigned int hb;
  memcpy(&hb, &hh, 4);
  bucket[offs[d] + pos] = make_uint2((unsigned int)src[e], hb);
}

// ---------------- per-node gather (GAT softmax-aggregate) ----------------
#define FMA4(A, H) { A.x += ex * H.x; A.y += ex * H.y; A.z += ex * H.z; A.w += ex * H.w; }

__global__ __launch_bounds__(256) void k_gather(
    const uint2* __restrict__ bucket, const int* __restrict__ offs,
    const float* __restrict__ a_s, const float* __restrict__ a_d,
    const float* __restrict__ h,
    const float* __restrict__ We, const float* __restrict__ aew,
    const float* __restrict__ bias,
    float* __restrict__ outv, float* __restrict__ bnsum, float* __restrict__ bnsq,
    int do_bn, int n) {
  int i = blockIdx.x * 256 + threadIdx.x;
  float we0 = 0.f, we1 = 0.f;
  #pragma unroll
  for (int c = 0; c < C; ++c) { we0 += We[c] * aew[c]; we1 += We[C + c] * aew[c]; }
  float v[C];
  #pragma unroll
  for (int c = 0; c < C; ++c) v[c] = 0.f;
  if (i < n) {
    int o0 = offs[i], o1 = offs[i + 1];
    float adi = a_d[i];
    float4 A0 = make_float4(0, 0, 0, 0), A1 = A0, A2 = A0, A3 = A0;
    float den = 0.f, lax = 0.f, lay = 0.f;
    for (int e = o0; e < o1; ++e) {
      uint2 r = bucket[e];
      int s = (int)r.x;
      __half2 hh;
      memcpy(&hh, &r.y, 4);
      float2 eaf = __half22float2(hh);
      float lg = a_s[s] + adi + eaf.x * we0 + eaf.y * we1;
      lg = lg > 0.f ? lg : 0.2f * lg;
      float ex = __expf(lg);
      den += ex; lax += eaf.x; lay += eaf.y;
      const float4* hp = (const float4*)&h[(size_t)s * C];
      float4 h0 = hp[0], h1 = hp[1], h2 = hp[2], h3 = hp[3];
      FMA4(A0, h0); FMA4(A1, h1); FMA4(A2, h2); FMA4(A3, h3);
    }
    // self loop with mean edge attr
    float dgc = fmaxf((float)(o1 - o0), 1.f);
    float lg = a_s[i] + adi + (lax * we0 + lay * we1) / dgc;
    lg = lg > 0.f ? lg : 0.2f * lg;
    float ex = __expf(lg);
    den += ex;
    const float4* hp = (const float4*)&h[(size_t)i * C];
    float4 h0 = hp[0], h1 = hp[1], h2 = hp[2], h3 = hp[3];
    FMA4(A0, h0); FMA4(A1, h1); FMA4(A2, h2); FMA4(A3, h3);
    float inv = 1.f / den;
    float acc[C] = {A0.x, A0.y, A0.z, A0.w, A1.x, A1.y, A1.z, A1.w,
                    A2.x, A2.y, A2.z, A2.w, A3.x, A3.y, A3.z, A3.w};
    #pragma unroll
    for (int c = 0; c < C; ++c) v[c] = fmaxf(acc[c] * inv + bias[c], 0.f);
    float4* op = (float4*)&outv[(size_t)i * C];
    op[0] = make_float4(v[0], v[1], v[2], v[3]);
    op[1] = make_float4(v[4], v[5], v[6], v[7]);
    op[2] = make_float4(v[8], v[9], v[10], v[11]);
    op[3] = make_float4(v[12], v[13], v[14], v[15]);
  }
  if (do_bn) {
    #pragma unroll
    for (int c = 0; c < C; ++c) {
      float s = v[c], q = v[c] * v[c];
      for (int o = 32; o > 0; o >>= 1) { s += __shfl_down(s, o); q += __shfl_down(q, o); }
      if ((threadIdx.x & 63) == 0) { atomicAdd(&bnsum[c], s); atomicAdd(&bnsq[c], q); }
    }
  }
}

__global__ void k_bnp(const float* __restrict__ bnsum, const float* __restrict__ bnsq,
                      const float* __restrict__ g, const float* __restrict__ bb,
                      float* __restrict__ scale, float* __restrict__ shift, float invn) {
  int c = threadIdx.x;
  if (c >= C) return;
  float mean = bnsum[c] * invn;
  float var = bnsq[c] * invn - mean * mean;
  float s = g[c] * rsqrtf(var + 1e-5f);
  scale[c] = s; shift[c] = bb[c] - mean * s;
}

// ---------------- BN + 16x16 matmul + a_s/a_d for layer 2 ----------------
__global__ __launch_bounds__(256) void k_node2(
    const float* __restrict__ outv, const float* __restrict__ scale,
    const float* __restrict__ shift, const float* __restrict__ W2,
    const float* __restrict__ asw, const float* __restrict__ adw,
    float* __restrict__ h, float* __restrict__ a_s, float* __restrict__ a_d, int n) {
  __shared__ float w2s[C * C];
  if (threadIdx.x < C * C) w2s[threadIdx.x] = W2[threadIdx.x];
  __syncthreads();
  int i = blockIdx.x * 256 + threadIdx.x;
  if (i >= n) return;
  float hn[C];
  #pragma unroll
  for (int c = 0; c < C; ++c) hn[c] = outv[(size_t)i * C + c] * scale[c] + shift[c];
  float h2[C];
  #pragma unroll
  for (int j = 0; j < C; ++j) {
    float acc = 0.f;
    #pragma unroll
    for (int c = 0; c < C; ++c) acc += hn[c] * w2s[c * C + j];
    h2[j] = acc;
  }
  float hs = 0.f, hd = 0.f;
  #pragma unroll
  for (int j = 0; j < C; ++j) { hs += h2[j] * asw[j]; hd += h2[j] * adw[j]; }
  a_s[i] = hs; a_d[i] = hd;
  float4* hp = (float4*)&h[(size_t)i * C];
  hp[0] = make_float4(h2[0], h2[1], h2[2], h2[3]);
  hp[1] = make_float4(h2[4], h2[5], h2[6], h2[7]);
  hp[2] = make_float4(h2[8], h2[9], h2[10], h2[11]);
  hp[3] = make_float4(h2[12], h2[13], h2[14], h2[15]);
}

// ---------------- graph segment offsets (batch is sorted) ----------------
__global__ void k_gstart(const int* __restrict__ batch, int* __restrict__ gs,
                         int n, int B_) {
  int g = blockIdx.x * blockDim.x + threadIdx.x;
  if (g > B_) return;
  if (g == B_) { gs[B_] = n; return; }
  int lo = 0, hi = n;
  while (lo < hi) { int mid = (lo + hi) >> 1; if (batch[mid] < g) lo = mid + 1; else hi = mid; }
  gs[g] = lo;
}

// one wave per graph: mean of outv rows
__global__ __launch_bounds__(256) void k_xe(
    const float* __restrict__ outv, const int* __restrict__ gs,
    float* __restrict__ xe, int B_) {
  int wave = blockIdx.x * 4 + (threadIdx.x >> 6);
  if (wave >= B_) return;
  int lane = threadIdx.x & 63;
  int c = lane & 15, sub = lane >> 4;
  int base = gs[wave], end = gs[wave + 1];
  float s = 0.f;
  for (int n0 = base + sub; n0 < end; n0 += 4) s += outv[(size_t)n0 * C + c];
  s += __shfl_down(s, 32);
  s += __shfl_down(s, 16);
  if (lane < 16) xe[(size_t)wave * C + c] = s / fmaxf((float)(end - base), 1.f);
}

// ---------------- D2RL tail (one block over B graphs) ----------------
__device__ __forceinline__ void head64(const float* z, const float* __restrict__ W,
                                       const float* __restrict__ b, float* __restrict__ o) {
  float l[64]; float mx = -1e30f;
  #pragma unroll
  for (int j = 0; j < 64; ++j) {
    float acc = b[j];
    #pragma unroll
    for (int c = 0; c < C; ++c) acc += z[c] * W[c * 64 + j];
    l[j] = acc; mx = fmaxf(mx, acc);
  }
  float ssum = 0.f;
  #pragma unroll
  for (int j = 0; j < 64; ++j) { l[j] = expf(l[j] - mx); ssum += l[j]; }
  float inv = 1.f / ssum;
  #pragma unroll
  for (int j = 0; j < 64; ++j) o[j] = l[j] * inv;
}

__global__ __launch_bounds__(512) void k_tail(
    const float* __restrict__ xe_in,
    const float* __restrict__ gL1, const float* __restrict__ bL1,
    const float* __restrict__ Wl1, const float* __restrict__ bl1,
    const float* __restrict__ gL2, const float* __restrict__ bL2,
    const float* __restrict__ Wl2, const float* __restrict__ bl2,
    const float* __restrict__ gL3, const float* __restrict__ bL3,
    const float* __restrict__ Wl3, const float* __restrict__ bl3,
    const float* __restrict__ Wx, const float* __restrict__ bx,
    const float* __restrict__ Wy, const float* __restrict__ by,
    const float* __restrict__ Wr, const float* __restrict__ br,
    float* __restrict__ out, int B_) {
  __shared__ float ssum[2 * C], ssq[2 * C], sc[2 * C], sh[2 * C];
  int t = threadIdx.x;
  float invB = 1.f / (float)B_;
  float xe[C];
  #pragma unroll
  for (int c = 0; c < C; ++c) xe[c] = xe_in[(size_t)t * C + c];

  // ---- BN1 over xe ----
  if (t < 2 * C) { ssum[t] = 0.f; ssq[t] = 0.f; }
  __syncthreads();
  #pragma unroll
  for (int c = 0; c < C; ++c) {
    float s = xe[c], q = xe[c] * xe[c];
    for (int o = 32; o > 0; o >>= 1) { s += __shfl_down(s, o); q += __shfl_down(q, o); }
    if ((t & 63) == 0) { atomicAdd(&ssum[c], s); atomicAdd(&ssq[c], q); }
  }
  __syncthreads();
  if (t < C) {
    float mean = ssum[t] * invB, var = ssq[t] * invB - mean * mean;
    float s = gL1[t] * rsqrtf(var + 1e-5f);
    sc[t] = s; sh[t] = bL1[t] - mean * s;
  }
  __syncthreads();
  float z[C];
  #pragma unroll
  for (int j = 0; j < C; ++j) {
    float acc = bl1[j];
    #pragma unroll
    for (int c = 0; c < C; ++c) acc += (xe[c] * sc[c] + sh[c]) * Wl1[c * C + j];
    z[j] = fmaxf(acc, 0.f);
  }
  __syncthreads();

  // ---- BN2 over [z, xe] ----
  if (t < 2 * C) { ssum[t] = 0.f; ssq[t] = 0.f; }
  __syncthreads();
  #pragma unroll
  for (int c = 0; c < C; ++c) {
    float s = z[c], q = z[c] * z[c];
    for (int o = 32; o > 0; o >>= 1) { s += __shfl_down(s, o); q += __shfl_down(q, o); }
    if ((t & 63) == 0) { atomicAdd(&ssum[c], s); atomicAdd(&ssq[c], q); }
    float s2 = xe[c], q2 = xe[c] * xe[c];
    for (int o = 32; o > 0; o >>= 1) { s2 += __shfl_down(s2, o); q2 += __shfl_down(q2, o); }
    if ((t & 63) == 0) { atomicAdd(&ssum[C + c], s2); atomicAdd(&ssq[C + c], q2); }
  }
  __syncthreads();
  if (t < 2 * C) {
    float mean = ssum[t] * invB, var = ssq[t] * invB - mean * mean;
    float s = gL2[t] * rsqrtf(var + 1e-5f);
    sc[t] = s; sh[t] = bL2[t] - mean * s;
  }
  __syncthreads();
  float z2[C];
  #pragma unroll
  for (int j = 0; j < C; ++j) {
    float acc = bl2[j];
    #pragma unroll
    for (int c = 0; c < C; ++c) acc += (z[c] * sc[c] + sh[c]) * Wl2[c * C + j];
    #pragma unroll
    for (int c = 0; c < C; ++c) acc += (xe[c] * sc[C + c] + sh[C + c]) * Wl2[(C + c) * C + j];
    z2[j] = fmaxf(acc, 0.f);
  }
  __syncthreads();

  // ---- BN3 over [z2, xe] ----
  if (t < 2 * C) { ssum[t] = 0.f; ssq[t] = 0.f; }
  __syncthreads();
  #pragma unroll
  for (int c = 0; c < C; ++c) {
    float s = z2[c], q = z2[c] * z2[c];
    for (int o = 32; o > 0; o >>= 1) { s += __shfl_down(s, o); q += __shfl_down(q, o); }
    if ((t & 63) == 0) { atomicAdd(&ssum[c], s); atomicAdd(&ssq[c], q); }
    float s2 = xe[c], q2 = xe[c] * xe[c];
    for (int o = 32; o > 0; o >>= 1) { s2 += __shfl_down(s2, o); q2 += __shfl_down(q2, o); }
    if ((t & 63) == 0) { atomicAdd(&ssum[C + c], s2); atomicAdd(&ssq[C + c], q2); }
  }
  __syncthreads();
  if (t < 2 * C) {
    float mean = ssum[t] * invB, var = ssq[t] * invB - mean * mean;
    float s = gL3[t] * rsqrtf(var + 1e-5f);
    sc[t] = s; sh[t] = bL3[t] - mean * s;
  }
  __syncthreads();
  float z3[C];
  #pragma unroll
  for (int j = 0; j < C; ++j) {
    float acc = bl3[j];
    #pragma unroll
    for (int c = 0; c < C; ++c) acc += (z2[c] * sc[c] + sh[c]) * Wl3[c * C + j];
    #pragma unroll
    for (int c = 0; c < C; ++c) acc += (xe[c] * sc[C + c] + sh[C + c]) * Wl3[(C + c) * C + j];
    z3[j] = fmaxf(acc, 0.f);
  }

  head64(z3, Wx, bx, out + (size_t)t * 64);
  head64(z3, Wy, by, out + (size_t)B_ * 64 + (size_t)t * 64);
  float r[4]; float mx = -1e30f;
  #pragma unroll
  for (int j = 0; j < 4; ++j) {
    float acc = br[j];
    #pragma unroll
    for (int c = 0; c < C; ++c) acc += z3[c] * Wr[c * 4 + j];
    r[j] = acc; mx = fmaxf(mx, acc);
  }
  float ssm = 0.f;
  #pragma unroll
  for (int j = 0; j < 4; ++j) { r[j] = expf(r[j] - mx); ssm += r[j]; }
  #pragma unroll
  for (int j = 0; j < 4; ++j) out[(size_t)B_ * 128 + (size_t)t * 4 + j] = r[j] / ssm;
}

extern "C" void kernel_launch(void* const* d_in, const int* in_sizes, int n_in,
                              void* d_out, int out_size, void* d_ws, size_t ws_size,
                              hipStream_t stream) {
  const float* x     = (const float*)d_in[0];
  const int*   eidx  = (const int*)d_in[1];
  const float* eattr = (const float*)d_in[2];
  const int*   batch = (const int*)d_in[3];
  const float* W1  = (const float*)d_in[4];
  const float* We1 = (const float*)d_in[5];
  const float* as1 = (const float*)d_in[6];
  const float* ad1 = (const float*)d_in[7];
  const float* ae1 = (const float*)d_in[8];
  const float* b1  = (const float*)d_in[9];
  const float* g1  = (const float*)d_in[10];
  const float* bb1 = (const float*)d_in[11];
  const float* W2  = (const float*)d_in[12];
  const float* We2 = (const float*)d_in[13];
  const float* as2 = (const float*)d_in[14];
  const float* ad2 = (const float*)d_in[15];
  const float* ae2 = (const float*)d_in[16];
  const float* b2  = (const float*)d_in[17];
  const float* gL1 = (const float*)d_in[18];
  const float* bL1 = (const float*)d_in[19];
  const float* Wl1 = (const float*)d_in[20];
  const float* bl1 = (const float*)d_in[21];
  const float* gL2 = (const float*)d_in[22];
  const float* bL2 = (const float*)d_in[23];
  const float* Wl2 = (const float*)d_in[24];
  const float* bl2 = (const float*)d_in[25];
  const float* gL3 = (const float*)d_in[26];
  const float* bL3 = (const float*)d_in[27];
  const float* Wl3 = (const float*)d_in[28];
  const float* bl3 = (const float*)d_in[29];
  const float* Wx  = (const float*)d_in[30];
  const float* bx  = (const float*)d_in[31];
  const float* Wy  = (const float*)d_in[32];
  const float* by  = (const float*)d_in[33];
  const float* Wr  = (const float*)d_in[34];
  const float* br  = (const float*)d_in[35];

  int N = in_sizes[3];
  int E = in_sizes[2] / 2;
  int B = out_size / 132;
  int nblk = (N + 511) / 512;

  char* w = (char*)d_ws;
  size_t o = 0;
  auto alloc = [&](size_t bytes) { char* p = w + o; o += (bytes + 15) & ~15ull; return p; };
  uint2* bucket  = (uint2*)alloc((size_t)E * 8);
  float* h       = (float*)alloc((size_t)N * C * 4);
  float* outv    = (float*)alloc((size_t)N * C * 4);
  float* a_s     = (float*)alloc((size_t)N * 4);
  float* a_d     = (float*)alloc((size_t)N * 4);
  int*   counts  = (int*)alloc((size_t)N * 4);
  int*   cursor  = (int*)alloc((size_t)N * 4);
  int*   offs    = (int*)alloc((size_t)(N + 4) * 4);
  int*   bsum    = (int*)alloc((size_t)(nblk + 4) * 4);
  float* bn      = (float*)alloc(64 * 4);        // [0:16)=sum [16:32)=sq [32:48)=scale [48:64)=shift
  float* xe      = (float*)alloc((size_t)B * C * 4);
  int*   gs      = (int*)alloc((size_t)(B + 4) * 4);

  const int* src = eidx;
  const int* dst = eidx + E;
  int ebl = (E + 255) / 256, nbl = (N + 255) / 256;

  // zero what must be zero (counts+cursor are adjacent)
  hipMemsetAsync(counts, 0, (size_t)2 * ((size_t)N * 4 + 15 & ~15ull), stream);
  hipMemsetAsync(bn, 0, 32 * 4, stream);

  k_gemm1<<<(N + 63) / 64, 256, 0, stream>>>(x, W1, as1, ad1, h, a_s, a_d, N);
  k_hist<<<ebl, 256, 0, stream>>>(dst, counts, N ? E : 0);
  k_scan1<<<nblk, 512, 0, stream>>>(counts, bsum, N);
  k_scan2<<<1, 1, 0, stream>>>(bsum, offs, nblk, N);
  k_scan3<<<nblk, 512, 0, stream>>>(counts, bsum, offs, N);
  k_scatter<<<ebl, 256, 0, stream>>>(src, dst, (const float2*)eattr, offs, cursor, bucket, E);
  k_gather<<<nbl, 256, 0, stream>>>(bucket, offs, a_s, a_d, h, We1, ae1, b1,
                                    outv, bn, bn + 16, 1, N);
  k_bnp<<<1, 64, 0, stream>>>(bn, bn + 16, g1, bb1, bn + 32, bn + 48, 1.f / (float)N);
  k_node2<<<nbl, 256, 0, stream>>>(outv, bn + 32, bn + 48, W2, as2, ad2, h, a_s, a_d, N);
  k_gather<<<nbl, 256, 0, stream>>>(bucket, offs, a_s, a_d, h, We2, ae2, b2,
                                    outv, bn, bn + 16, 0, N);
  k_gstart<<<(B + 1 + 255) / 256, 256, 0, stream>>>(batch, gs, N, B);
  k_xe<<<(B + 3) / 4, 256, 0, stream>>>(outv, gs, xe, B);
  k_tail<<<1, B, 0, stream>>>(xe, gL1, bL1, Wl1, bl1, gL2, bL2, Wl2, bl2,
                              gL3, bL3, Wl3, bl3, Wx, bx, Wy, by, Wr, br,
                              (float*)d_out, B);
}

// Round 3
// 965.808 us; speedup vs baseline: 7.3850x; 1.3137x over previous
//
#include <hip/hip_runtime.h>
#include <hip/hip_fp16.h>
#include <math.h>

#define C 16
#define FIN 128

// ---------------- GEMM x@W1 (100k x 128 x 16) + fused a_s/a_d ----------------
__global__ __launch_bounds__(256) void k_gemm1(
    const float* __restrict__ x, const float* __restrict__ W,
    const float* __restrict__ asw, const float* __restrict__ adw,
    float* __restrict__ h, float* __restrict__ a_s, float* __restrict__ a_d, int n) {
  __shared__ float xs[64 * 129];
  __shared__ float Ws[FIN * C];
  __shared__ float pAs[4][64], pAd[4][64];
  int t = threadIdx.x;
  int node0 = blockIdx.x * 64;
  for (int i = t; i < FIN * C; i += 256) Ws[i] = W[i];
  for (int i = t; i < 64 * FIN; i += 256) {
    int r = i >> 7, c = i & 127;
    int node = node0 + r;
    xs[r * 129 + c] = (node < n) ? x[(size_t)node * FIN + c] : 0.f;
  }
  __syncthreads();
  int nn = t & 63, cg = (t >> 6) * 4, grp = t >> 6;
  float a0 = 0.f, a1 = 0.f, a2 = 0.f, a3 = 0.f;
  const float* xr = &xs[nn * 129];
  #pragma unroll 8
  for (int k = 0; k < FIN; ++k) {
    float xv = xr[k];
    const float* wr = &Ws[k * C + cg];
    a0 += xv * wr[0]; a1 += xv * wr[1]; a2 += xv * wr[2]; a3 += xv * wr[3];
  }
  int node = node0 + nn;
  if (node < n) {
    float4* outp = (float4*)&h[(size_t)node * C + cg];
    *outp = make_float4(a0, a1, a2, a3);
  }
  pAs[grp][nn] = a0 * asw[cg] + a1 * asw[cg + 1] + a2 * asw[cg + 2] + a3 * asw[cg + 3];
  pAd[grp][nn] = a0 * adw[cg] + a1 * adw[cg + 1] + a2 * adw[cg + 2] + a3 * adw[cg + 3];
  __syncthreads();
  if (t < 64 && node0 + t < n) {
    a_s[node0 + t] = pAs[0][t] + pAs[1][t] + pAs[2][t] + pAs[3][t];
    a_d[node0 + t] = pAd[0][t] + pAd[1][t] + pAd[2][t] + pAd[3][t];
  }
}

// ---------------- CSR build ----------------
// hist + rank in one pass: the atomic's return value IS the intra-bucket slot
__global__ __launch_bounds__(256) void k_hist_rank(
    const int* __restrict__ dst, int* __restrict__ counts,
    int* __restrict__ rank, int ne) {
  int e = blockIdx.x * 256 + threadIdx.x;
  if (e < ne) rank[e] = atomicAdd(&counts[dst[e]], 1);
}

__global__ __launch_bounds__(512) void k_scan1(const int* __restrict__ counts,
                                               int* __restrict__ bsum, int n) {
  __shared__ int sd[512];
  int i = blockIdx.x * 512 + threadIdx.x;
  sd[threadIdx.x] = (i < n) ? counts[i] : 0;
  __syncthreads();
  for (int s = 256; s > 0; s >>= 1) {
    if (threadIdx.x < s) sd[threadIdx.x] += sd[threadIdx.x + s];
    __syncthreads();
  }
  if (threadIdx.x == 0) bsum[blockIdx.x] = sd[0];
}

// parallel exclusive scan of block sums (nblk <= 512)
__global__ __launch_bounds__(512) void k_scan2(int* __restrict__ bsum,
                                               int* __restrict__ offs,
                                               int nblk, int n) {
  __shared__ int sd[512];
  int t = threadIdx.x;
  int v = (t < nblk) ? bsum[t] : 0;
  sd[t] = v;
  __syncthreads();
  for (int off = 1; off < 512; off <<= 1) {
    int x = (t >= off) ? sd[t - off] : 0;
    __syncthreads();
    sd[t] += x;
    __syncthreads();
  }
  if (t < nblk) bsum[t] = sd[t] - v;
  if (t == nblk - 1) offs[n] = sd[t];
}

__global__ __launch_bounds__(512) void k_scan3(const int* __restrict__ counts,
                                               const int* __restrict__ bsum,
                                               int* __restrict__ offs, int n) {
  __shared__ int sd[512];
  int t = threadIdx.x;
  int i = blockIdx.x * 512 + t;
  int v = (i < n) ? counts[i] : 0;
  sd[t] = v;
  __syncthreads();
  for (int off = 1; off < 512; off <<= 1) {
    int x = (t >= off) ? sd[t - off] : 0;
    __syncthreads();
    sd[t] += x;
    __syncthreads();
  }
  if (i < n) offs[i] = bsum[blockIdx.x] + sd[t] - v;
}

// atomic-free scatter using precomputed rank
__global__ __launch_bounds__(256) void k_scatter(
    const int* __restrict__ src, const int* __restrict__ dst,
    const float2* __restrict__ ea, const int* __restrict__ offs,
    const int* __restrict__ rank, uint2* __restrict__ bucket, int ne) {
  int e = blockIdx.x * 256 + threadIdx.x;
  if (e >= ne) return;
  int d = dst[e];
  float2 a = ea[e];
  __half2 hh = __floats2half2_rn(a.x, a.y);
  unsigned int hb;
  memcpy(&hb, &hh, 4);
  bucket[offs[d] + rank[e]] = make_uint2((unsigned int)src[e], hb);
}

// ---------------- per-node gather: 16 lanes per node, edge-parallel ----------------
__global__ __launch_bounds__(256) void k_gather(
    const uint2* __restrict__ bucket, const int* __restrict__ offs,
    const float* __restrict__ a_s, const float* __restrict__ a_d,
    const float* __restrict__ h,
    const float* __restrict__ We, const float* __restrict__ aew,
    const float* __restrict__ bias,
    float* __restrict__ outv, float* __restrict__ bnsum, float* __restrict__ bnsq,
    int do_bn, int n) {
  __shared__ float sbn[32];
  int t = threadIdx.x;
  if (t < 32) sbn[t] = 0.f;
  __syncthreads();

  int node = blockIdx.x * 16 + (t >> 4);
  int l = t & 15;
  float we0 = 0.f, we1 = 0.f;
  #pragma unroll
  for (int c = 0; c < C; ++c) { we0 += We[c] * aew[c]; we1 += We[C + c] * aew[c]; }

  float acc[C];
  #pragma unroll
  for (int c = 0; c < C; ++c) acc[c] = 0.f;
  float den = 0.f, lax = 0.f, lay = 0.f;
  int o0 = 0, o1 = 0;
  float adi = 0.f, asi = 0.f;
  if (node < n) {
    o0 = offs[node]; o1 = offs[node + 1];
    adi = a_d[node]; asi = a_s[node];
    for (int e = o0 + l; e < o1; e += 16) {
      uint2 r = bucket[e];
      int s = (int)r.x;
      __half2 hh;
      memcpy(&hh, &r.y, 4);
      float2 eaf = __half22float2(hh);
      float lg = a_s[s] + adi + eaf.x * we0 + eaf.y * we1;
      lg = lg > 0.f ? lg : 0.2f * lg;
      float ex = __expf(lg);
      den += ex; lax += eaf.x; lay += eaf.y;
      const float4* hp = (const float4*)&h[(size_t)s * C];
      float4 h0 = hp[0], h1 = hp[1], h2 = hp[2], h3 = hp[3];
      acc[0] += ex * h0.x; acc[1] += ex * h0.y; acc[2] += ex * h0.z; acc[3] += ex * h0.w;
      acc[4] += ex * h1.x; acc[5] += ex * h1.y; acc[6] += ex * h1.z; acc[7] += ex * h1.w;
      acc[8] += ex * h2.x; acc[9] += ex * h2.y; acc[10] += ex * h2.z; acc[11] += ex * h2.w;
      acc[12] += ex * h3.x; acc[13] += ex * h3.y; acc[14] += ex * h3.z; acc[15] += ex * h3.w;
    }
  }
  // butterfly reduce within the 16-lane node group
  #pragma unroll
  for (int off = 1; off < 16; off <<= 1) {
    den += __shfl_xor(den, off);
    lax += __shfl_xor(lax, off);
    lay += __shfl_xor(lay, off);
    #pragma unroll
    for (int c = 0; c < C; ++c) acc[c] += __shfl_xor(acc[c], off);
  }

  float v = 0.f;
  if (node < n) {
    float dgc = fmaxf((float)(o1 - o0), 1.f);
    float lg = asi + adi + (lax * we0 + lay * we1) / dgc;
    lg = lg > 0.f ? lg : 0.2f * lg;
    float ex = __expf(lg);
    float hi = h[(size_t)node * C + l];           // coalesced: lane l -> channel l
    float tot = acc[l] + ex * hi;
    den += ex;
    v = fmaxf(tot / den + bias[l], 0.f);
    outv[(size_t)node * C + l] = v;               // coalesced
  }
  if (do_bn) {
    float s = v, q = v * v;
    s += __shfl_down(s, 32); s += __shfl_down(s, 16);
    q += __shfl_down(q, 32); q += __shfl_down(q, 16);
    if ((t & 63) < 16) {
      atomicAdd(&sbn[l], s);
      atomicAdd(&sbn[16 + l], q);
    }
    __syncthreads();
    if (t < 16) atomicAdd(&bnsum[t], sbn[t]);
    else if (t < 32) atomicAdd(&bnsq[t - 16], sbn[t]);
  }
}

__global__ void k_bnp(const float* __restrict__ bnsum, const float* __restrict__ bnsq,
                      const float* __restrict__ g, const float* __restrict__ bb,
                      float* __restrict__ scale, float* __restrict__ shift, float invn) {
  int c = threadIdx.x;
  if (c >= C) return;
  float mean = bnsum[c] * invn;
  float var = bnsq[c] * invn - mean * mean;
  float s = g[c] * rsqrtf(var + 1e-5f);
  scale[c] = s; shift[c] = bb[c] - mean * s;
}

// ---------------- BN + 16x16 matmul + a_s/a_d for layer 2 ----------------
__global__ __launch_bounds__(256) void k_node2(
    const float* __restrict__ outv, const float* __restrict__ scale,
    const float* __restrict__ shift, const float* __restrict__ W2,
    const float* __restrict__ asw, const float* __restrict__ adw,
    float* __restrict__ h, float* __restrict__ a_s, float* __restrict__ a_d, int n) {
  __shared__ float w2s[C * C];
  if (threadIdx.x < C * C) w2s[threadIdx.x] = W2[threadIdx.x];
  __syncthreads();
  int i = blockIdx.x * 256 + threadIdx.x;
  if (i >= n) return;
  float hn[C];
  #pragma unroll
  for (int c = 0; c < C; ++c) hn[c] = outv[(size_t)i * C + c] * scale[c] + shift[c];
  float h2[C];
  #pragma unroll
  for (int j = 0; j < C; ++j) {
    float acc = 0.f;
    #pragma unroll
    for (int c = 0; c < C; ++c) acc += hn[c] * w2s[c * C + j];
    h2[j] = acc;
  }
  float hs = 0.f, hd = 0.f;
  #pragma unroll
  for (int j = 0; j < C; ++j) { hs += h2[j] * asw[j]; hd += h2[j] * adw[j]; }
  a_s[i] = hs; a_d[i] = hd;
  float4* hp = (float4*)&h[(size_t)i * C];
  hp[0] = make_float4(h2[0], h2[1], h2[2], h2[3]);
  hp[1] = make_float4(h2[4], h2[5], h2[6], h2[7]);
  hp[2] = make_float4(h2[8], h2[9], h2[10], h2[11]);
  hp[3] = make_float4(h2[12], h2[13], h2[14], h2[15]);
}

// ---------------- graph segment offsets (batch is sorted) ----------------
__global__ void k_gstart(const int* __restrict__ batch, int* __restrict__ gs,
                         int n, int B_) {
  int g = blockIdx.x * blockDim.x + threadIdx.x;
  if (g > B_) return;
  if (g == B_) { gs[B_] = n; return; }
  int lo = 0, hi = n;
  while (lo < hi) { int mid = (lo + hi) >> 1; if (batch[mid] < g) lo = mid + 1; else hi = mid; }
  gs[g] = lo;
}

__global__ __launch_bounds__(256) void k_xe(
    const float* __restrict__ outv, const int* __restrict__ gs,
    float* __restrict__ xe, int B_) {
  int wave = blockIdx.x * 4 + (threadIdx.x >> 6);
  if (wave >= B_) return;
  int lane = threadIdx.x & 63;
  int c = lane & 15, sub = lane >> 4;
  int base = gs[wave], end = gs[wave + 1];
  float s = 0.f;
  for (int n0 = base + sub; n0 < end; n0 += 4) s += outv[(size_t)n0 * C + c];
  s += __shfl_down(s, 32);
  s += __shfl_down(s, 16);
  if (lane < 16) xe[(size_t)wave * C + c] = s / fmaxf((float)(end - base), 1.f);
}

// ---------------- D2RL tail ----------------
__device__ __forceinline__ void head64(const float* z, const float* __restrict__ W,
                                       const float* __restrict__ b, float* __restrict__ o) {
  float l[64]; float mx = -1e30f;
  #pragma unroll
  for (int j = 0; j < 64; ++j) {
    float acc = b[j];
    #pragma unroll
    for (int c = 0; c < C; ++c) acc += z[c] * W[c * 64 + j];
    l[j] = acc; mx = fmaxf(mx, acc);
  }
  float ssum = 0.f;
  #pragma unroll
  for (int j = 0; j < 64; ++j) { l[j] = expf(l[j] - mx); ssum += l[j]; }
  float inv = 1.f / ssum;
  #pragma unroll
  for (int j = 0; j < 64; ++j) o[j] = l[j] * inv;
}

__global__ __launch_bounds__(512) void k_tail(
    const float* __restrict__ xe_in,
    const float* __restrict__ gL1, const float* __restrict__ bL1,
    const float* __restrict__ Wl1, const float* __restrict__ bl1,
    const float* __restrict__ gL2, const float* __restrict__ bL2,
    const float* __restrict__ Wl2, const float* __restrict__ bl2,
    const float* __restrict__ gL3, const float* __restrict__ bL3,
    const float* __restrict__ Wl3, const float* __restrict__ bl3,
    const float* __restrict__ Wx, const float* __restrict__ bx,
    const float* __restrict__ Wy, const float* __restrict__ by,
    const float* __restrict__ Wr, const float* __restrict__ br,
    float* __restrict__ out, int B_) {
  __shared__ float ssum[2 * C], ssq[2 * C], sc[2 * C], sh[2 * C];
  int t = threadIdx.x;
  float invB = 1.f / (float)B_;
  float xe[C];
  #pragma unroll
  for (int c = 0; c < C; ++c) xe[c] = xe_in[(size_t)t * C + c];

  if (t < 2 * C) { ssum[t] = 0.f; ssq[t] = 0.f; }
  __syncthreads();
  #pragma unroll
  for (int c = 0; c < C; ++c) {
    float s = xe[c], q = xe[c] * xe[c];
    for (int o = 32; o > 0; o >>= 1) { s += __shfl_down(s, o); q += __shfl_down(q, o); }
    if ((t & 63) == 0) { atomicAdd(&ssum[c], s); atomicAdd(&ssq[c], q); }
  }
  __syncthreads();
  if (t < C) {
    float mean = ssum[t] * invB, var = ssq[t] * invB - mean * mean;
    float s = gL1[t] * rsqrtf(var + 1e-5f);
    sc[t] = s; sh[t] = bL1[t] - mean * s;
  }
  __syncthreads();
  float z[C];
  #pragma unroll
  for (int j = 0; j < C; ++j) {
    float acc = bl1[j];
    #pragma unroll
    for (int c = 0; c < C; ++c) acc += (xe[c] * sc[c] + sh[c]) * Wl1[c * C + j];
    z[j] = fmaxf(acc, 0.f);
  }
  __syncthreads();

  if (t < 2 * C) { ssum[t] = 0.f; ssq[t] = 0.f; }
  __syncthreads();
  #pragma unroll
  for (int c = 0; c < C; ++c) {
    float s = z[c], q = z[c] * z[c];
    for (int o = 32; o > 0; o >>= 1) { s += __shfl_down(s, o); q += __shfl_down(q, o); }
    if ((t & 63) == 0) { atomicAdd(&ssum[c], s); atomicAdd(&ssq[c], q); }
    float s2 = xe[c], q2 = xe[c] * xe[c];
    for (int o = 32; o > 0; o >>= 1) { s2 += __shfl_down(s2, o); q2 += __shfl_down(q2, o); }
    if ((t & 63) == 0) { atomicAdd(&ssum[C + c], s2); atomicAdd(&ssq[C + c], q2); }
  }
  __syncthreads();
  if (t < 2 * C) {
    float mean = ssum[t] * invB, var = ssq[t] * invB - mean * mean;
    float s = gL2[t] * rsqrtf(var + 1e-5f);
    sc[t] = s; sh[t] = bL2[t] - mean * s;
  }
  __syncthreads();
  float z2[C];
  #pragma unroll
  for (int j = 0; j < C; ++j) {
    float acc = bl2[j];
    #pragma unroll
    for (int c = 0; c < C; ++c) acc += (z[c] * sc[c] + sh[c]) * Wl2[c * C + j];
    #pragma unroll
    for (int c = 0; c < C; ++c) acc += (xe[c] * sc[C + c] + sh[C + c]) * Wl2[(C + c) * C + j];
    z2[j] = fmaxf(acc, 0.f);
  }
  __syncthreads();

  if (t < 2 * C) { ssum[t] = 0.f; ssq[t] = 0.f; }
  __syncthreads();
  #pragma unroll
  for (int c = 0; c < C; ++c) {
    float s = z2[c], q = z2[c] * z2[c];
    for (int o = 32; o > 0; o >>= 1) { s += __shfl_down(s, o); q += __shfl_down(q, o); }
    if ((t & 63) == 0) { atomicAdd(&ssum[c], s); atomicAdd(&ssq[c], q); }
    float s2 = xe[c], q2 = xe[c] * xe[c];
    for (int o = 32; o > 0; o >>= 1) { s2 += __shfl_down(s2, o); q2 += __shfl_down(q2, o); }
    if ((t & 63) == 0) { atomicAdd(&ssum[C + c], s2); atomicAdd(&ssq[C + c], q2); }
  }
  __syncthreads();
  if (t < 2 * C) {
    float mean = ssum[t] * invB, var = ssq[t] * invB - mean * mean;
    float s = gL3[t] * rsqrtf(var + 1e-5f);
    sc[t] = s; sh[t] = bL3[t] - mean * s;
  }
  __syncthreads();
  float z3[C];
  #pragma unroll
  for (int j = 0; j < C; ++j) {
    float acc = bl3[j];
    #pragma unroll
    for (int c = 0; c < C; ++c) acc += (z2[c] * sc[c] + sh[c]) * Wl3[c * C + j];
    #pragma unroll
    for (int c = 0; c < C; ++c) acc += (xe[c] * sc[C + c] + sh[C + c]) * Wl3[(C + c) * C + j];
    z3[j] = fmaxf(acc, 0.f);
  }

  head64(z3, Wx, bx, out + (size_t)t * 64);
  head64(z3, Wy, by, out + (size_t)B_ * 64 + (size_t)t * 64);
  float r[4]; float mx = -1e30f;
  #pragma unroll
  for (int j = 0; j < 4; ++j) {
    float acc = br[j];
    #pragma unroll
    for (int c = 0; c < C; ++c) acc += z3[c] * Wr[c * 4 + j];
    r[j] = acc; mx = fmaxf(mx, acc);
  }
  float ssm = 0.f;
  #pragma unroll
  for (int j = 0; j < 4; ++j) { r[j] = expf(r[j] - mx); ssm += r[j]; }
  #pragma unroll
  for (int j = 0; j < 4; ++j) out[(size_t)B_ * 128 + (size_t)t * 4 + j] = r[j] / ssm;
}

extern "C" void kernel_launch(void* const* d_in, const int* in_sizes, int n_in,
                              void* d_out, int out_size, void* d_ws, size_t ws_size,
                              hipStream_t stream) {
  const float* x     = (const float*)d_in[0];
  const int*   eidx  = (const int*)d_in[1];
  const float* eattr = (const float*)d_in[2];
  const int*   batch = (const int*)d_in[3];
  const float* W1  = (const float*)d_in[4];
  const float* We1 = (const float*)d_in[5];
  const float* as1 = (const float*)d_in[6];
  const float* ad1 = (const float*)d_in[7];
  const float* ae1 = (const float*)d_in[8];
  const float* b1  = (const float*)d_in[9];
  const float* g1  = (const float*)d_in[10];
  const float* bb1 = (const float*)d_in[11];
  const float* W2  = (const float*)d_in[12];
  const float* We2 = (const float*)d_in[13];
  const float* as2 = (const float*)d_in[14];
  const float* ad2 = (const float*)d_in[15];
  const float* ae2 = (const float*)d_in[16];
  const float* b2  = (const float*)d_in[17];
  const float* gL1 = (const float*)d_in[18];
  const float* bL1 = (const float*)d_in[19];
  const float* Wl1 = (const float*)d_in[20];
  const float* bl1 = (const float*)d_in[21];
  const float* gL2 = (const float*)d_in[22];
  const float* bL2 = (const float*)d_in[23];
  const float* Wl2 = (const float*)d_in[24];
  const float* bl2 = (const float*)d_in[25];
  const float* gL3 = (const float*)d_in[26];
  const float* bL3 = (const float*)d_in[27];
  const float* Wl3 = (const float*)d_in[28];
  const float* bl3 = (const float*)d_in[29];
  const float* Wx  = (const float*)d_in[30];
  const float* bx  = (const float*)d_in[31];
  const float* Wy  = (const float*)d_in[32];
  const float* by  = (const float*)d_in[33];
  const float* Wr  = (const float*)d_in[34];
  const float* br  = (const float*)d_in[35];

  int N = in_sizes[3];
  int E = in_sizes[2] / 2;
  int B = out_size / 132;
  int nblk = (N + 511) / 512;

  char* w = (char*)d_ws;
  size_t o = 0;
  auto alloc = [&](size_t bytes) { char* p = w + o; o += (bytes + 15) & ~15ull; return p; };
  uint2* bucket  = (uint2*)alloc((size_t)E * 8);
  int*   rank    = (int*)alloc((size_t)E * 4);
  float* h       = (float*)alloc((size_t)N * C * 4);
  float* outv    = (float*)alloc((size_t)N * C * 4);
  float* a_s     = (float*)alloc((size_t)N * 4);
  float* a_d     = (float*)alloc((size_t)N * 4);
  int*   counts  = (int*)alloc((size_t)N * 4);
  int*   offs    = (int*)alloc((size_t)(N + 4) * 4);
  int*   bsum    = (int*)alloc((size_t)(nblk + 4) * 4);
  float* bn      = (float*)alloc(64 * 4);   // sum[16] sq[16] scale[16] shift[16]
  float* xe      = (float*)alloc((size_t)B * C * 4);
  int*   gs      = (int*)alloc((size_t)(B + 4) * 4);

  const int* src = eidx;
  const int* dst = eidx + E;
  int ebl = (E + 255) / 256;
  int nbl = (N + 255) / 256;

  hipMemsetAsync(counts, 0, (size_t)N * 4, stream);
  hipMemsetAsync(bn, 0, 32 * 4, stream);

  k_gemm1<<<(N + 63) / 64, 256, 0, stream>>>(x, W1, as1, ad1, h, a_s, a_d, N);
  k_hist_rank<<<ebl, 256, 0, stream>>>(dst, counts, rank, E);
  k_scan1<<<nblk, 512, 0, stream>>>(counts, bsum, N);
  k_scan2<<<1, 512, 0, stream>>>(bsum, offs, nblk, N);
  k_scan3<<<nblk, 512, 0, stream>>>(counts, bsum, offs, N);
  k_scatter<<<ebl, 256, 0, stream>>>(src, dst, (const float2*)eattr, offs, rank, bucket, E);
  k_gather<<<(N + 15) / 16, 256, 0, stream>>>(bucket, offs, a_s, a_d, h, We1, ae1, b1,
                                              outv, bn, bn + 16, 1, N);
  k_bnp<<<1, 64, 0, stream>>>(bn, bn + 16, g1, bb1, bn + 32, bn + 48, 1.f / (float)N);
  k_node2<<<nbl, 256, 0, stream>>>(outv, bn + 32, bn + 48, W2, as2, ad2, h, a_s, a_d, N);
  k_gather<<<(N + 15) / 16, 256, 0, stream>>>(bucket, offs, a_s, a_d, h, We2, ae2, b2,
                                              outv, bn, bn + 16, 0, N);
  k_gstart<<<(B + 1 + 255) / 256, 256, 0, stream>>>(batch, gs, N, B);
  k_xe<<<(B + 3) / 4, 256, 0, stream>>>(outv, gs, xe, B);
  k_tail<<<1, B, 0, stream>>>(xe, gL1, bL1, Wl1, bl1, gL2, bL2, Wl2, bl2,
                              gL3, bL3, Wl3, bl3, Wx, bx, Wy, by, Wr, br,
                              (float*)d_out, B);
}

// Round 4
// 783.790 us; speedup vs baseline: 9.1001x; 1.2322x over previous
//
#include <hip/hip_runtime.h>
#include <hip/hip_fp16.h>
#include <math.h>

#define C 16
#define FIN 128

// ---------------- GEMM x@W1 (100k x 128 x 16) + fused a_s/a_d ----------------
__global__ __launch_bounds__(256) void k_gemm1(
    const float* __restrict__ x, const float* __restrict__ W,
    const float* __restrict__ asw, const float* __restrict__ adw,
    float* __restrict__ h, float* __restrict__ a_s, float* __restrict__ a_d, int n) {
  __shared__ float xs[64 * 129];
  __shared__ float Ws[FIN * C];
  __shared__ float pAs[4][64], pAd[4][64];
  int t = threadIdx.x;
  int node0 = blockIdx.x * 64;
  for (int i = t; i < FIN * C; i += 256) Ws[i] = W[i];
  for (int i = t; i < 64 * FIN; i += 256) {
    int r = i >> 7, c = i & 127;
    int node = node0 + r;
    xs[r * 129 + c] = (node < n) ? x[(size_t)node * FIN + c] : 0.f;
  }
  __syncthreads();
  int nn = t & 63, cg = (t >> 6) * 4, grp = t >> 6;
  float a0 = 0.f, a1 = 0.f, a2 = 0.f, a3 = 0.f;
  const float* xr = &xs[nn * 129];
  #pragma unroll 8
  for (int k = 0; k < FIN; ++k) {
    float xv = xr[k];
    const float* wr = &Ws[k * C + cg];
    a0 += xv * wr[0]; a1 += xv * wr[1]; a2 += xv * wr[2]; a3 += xv * wr[3];
  }
  int node = node0 + nn;
  if (node < n) {
    float4* outp = (float4*)&h[(size_t)node * C + cg];
    *outp = make_float4(a0, a1, a2, a3);
  }
  pAs[grp][nn] = a0 * asw[cg] + a1 * asw[cg + 1] + a2 * asw[cg + 2] + a3 * asw[cg + 3];
  pAd[grp][nn] = a0 * adw[cg] + a1 * adw[cg + 1] + a2 * adw[cg + 2] + a3 * adw[cg + 3];
  __syncthreads();
  if (t < 64 && node0 + t < n) {
    a_s[node0 + t] = pAs[0][t] + pAs[1][t] + pAs[2][t] + pAs[3][t];
    a_d[node0 + t] = pAd[0][t] + pAd[1][t] + pAd[2][t] + pAd[3][t];
  }
}

// ---------------- CSR build ----------------
__global__ __launch_bounds__(256) void k_hist_rank(
    const int* __restrict__ dst, int* __restrict__ counts,
    int* __restrict__ rank, int ne) {
  int e = blockIdx.x * 256 + threadIdx.x;
  if (e < ne) rank[e] = atomicAdd(&counts[dst[e]], 1);
}

__global__ __launch_bounds__(512) void k_scan1(const int* __restrict__ counts,
                                               int* __restrict__ bsum, int n) {
  __shared__ int sd[512];
  int i = blockIdx.x * 512 + threadIdx.x;
  sd[threadIdx.x] = (i < n) ? counts[i] : 0;
  __syncthreads();
  for (int s = 256; s > 0; s >>= 1) {
    if (threadIdx.x < s) sd[threadIdx.x] += sd[threadIdx.x + s];
    __syncthreads();
  }
  if (threadIdx.x == 0) bsum[blockIdx.x] = sd[0];
}

__global__ __launch_bounds__(512) void k_scan2(int* __restrict__ bsum,
                                               int* __restrict__ offs,
                                               int nblk, int n) {
  __shared__ int sd[512];
  int t = threadIdx.x;
  int v = (t < nblk) ? bsum[t] : 0;
  sd[t] = v;
  __syncthreads();
  for (int off = 1; off < 512; off <<= 1) {
    int x = (t >= off) ? sd[t - off] : 0;
    __syncthreads();
    sd[t] += x;
    __syncthreads();
  }
  if (t < nblk) bsum[t] = sd[t] - v;
  if (t == nblk - 1) offs[n] = sd[t];
}

__global__ __launch_bounds__(512) void k_scan3(const int* __restrict__ counts,
                                               const int* __restrict__ bsum,
                                               int* __restrict__ offs, int n) {
  __shared__ int sd[512];
  int t = threadIdx.x;
  int i = blockIdx.x * 512 + t;
  int v = (i < n) ? counts[i] : 0;
  sd[t] = v;
  __syncthreads();
  for (int off = 1; off < 512; off <<= 1) {
    int x = (t >= off) ? sd[t - off] : 0;
    __syncthreads();
    sd[t] += x;
    __syncthreads();
  }
  if (i < n) offs[i] = bsum[blockIdx.x] + sd[t] - v;
}

__global__ __launch_bounds__(256) void k_scatter(
    const int* __restrict__ src, const int* __restrict__ dst,
    const float2* __restrict__ ea, const int* __restrict__ offs,
    const int* __restrict__ rank, uint2* __restrict__ bucket, int ne) {
  int e = blockIdx.x * 256 + threadIdx.x;
  if (e >= ne) return;
  int d = dst[e];
  float2 a = ea[e];
  __half2 hh = __floats2half2_rn(a.x, a.y);
  unsigned int hb;
  memcpy(&hb, &hh, 4);
  bucket[offs[d] + rank[e]] = make_uint2((unsigned int)src[e], hb);
}

// ---------------- per-node gather: 16 lanes per node, edge-parallel ----------------
__global__ __launch_bounds__(256) void k_gather(
    const uint2* __restrict__ bucket, const int* __restrict__ offs,
    const float* __restrict__ a_s, const float* __restrict__ a_d,
    const float* __restrict__ h,
    const float* __restrict__ We, const float* __restrict__ aew,
    const float* __restrict__ bias,
    float* __restrict__ outv, float* __restrict__ bnsum, float* __restrict__ bnsq,
    int do_bn, int n) {
  __shared__ float sbn[32];
  int t = threadIdx.x;
  if (t < 32) sbn[t] = 0.f;
  __syncthreads();

  int node = blockIdx.x * 16 + (t >> 4);
  int l = t & 15;
  float we0 = 0.f, we1 = 0.f;
  #pragma unroll
  for (int c = 0; c < C; ++c) { we0 += We[c] * aew[c]; we1 += We[C + c] * aew[c]; }

  float acc[C];
  #pragma unroll
  for (int c = 0; c < C; ++c) acc[c] = 0.f;
  float den = 0.f, lax = 0.f, lay = 0.f;
  int o0 = 0, o1 = 0;
  float adi = 0.f, asi = 0.f;
  if (node < n) {
    o0 = offs[node]; o1 = offs[node + 1];
    adi = a_d[node]; asi = a_s[node];
    for (int e = o0 + l; e < o1; e += 16) {
      uint2 r = bucket[e];
      int s = (int)r.x;
      __half2 hh;
      memcpy(&hh, &r.y, 4);
      float2 eaf = __half22float2(hh);
      float lg = a_s[s] + adi + eaf.x * we0 + eaf.y * we1;
      lg = lg > 0.f ? lg : 0.2f * lg;
      float ex = __expf(lg);
      den += ex; lax += eaf.x; lay += eaf.y;
      const float4* hp = (const float4*)&h[(size_t)s * C];
      float4 h0 = hp[0], h1 = hp[1], h2 = hp[2], h3 = hp[3];
      acc[0] += ex * h0.x; acc[1] += ex * h0.y; acc[2] += ex * h0.z; acc[3] += ex * h0.w;
      acc[4] += ex * h1.x; acc[5] += ex * h1.y; acc[6] += ex * h1.z; acc[7] += ex * h1.w;
      acc[8] += ex * h2.x; acc[9] += ex * h2.y; acc[10] += ex * h2.z; acc[11] += ex * h2.w;
      acc[12] += ex * h3.x; acc[13] += ex * h3.y; acc[14] += ex * h3.z; acc[15] += ex * h3.w;
    }
  }
  #pragma unroll
  for (int off = 1; off < 16; off <<= 1) {
    den += __shfl_xor(den, off);
    lax += __shfl_xor(lax, off);
    lay += __shfl_xor(lay, off);
    #pragma unroll
    for (int c = 0; c < C; ++c) acc[c] += __shfl_xor(acc[c], off);
  }

  float v = 0.f;
  if (node < n) {
    float dgc = fmaxf((float)(o1 - o0), 1.f);
    float lg = asi + adi + (lax * we0 + lay * we1) / dgc;
    lg = lg > 0.f ? lg : 0.2f * lg;
    float ex = __expf(lg);
    float hi = h[(size_t)node * C + l];
    float tot = acc[l] + ex * hi;
    den += ex;
    v = fmaxf(tot / den + bias[l], 0.f);
    outv[(size_t)node * C + l] = v;
  }
  if (do_bn) {
    float s = v, q = v * v;
    s += __shfl_down(s, 32); s += __shfl_down(s, 16);
    q += __shfl_down(q, 32); q += __shfl_down(q, 16);
    if ((t & 63) < 16) {
      atomicAdd(&sbn[l], s);
      atomicAdd(&sbn[16 + l], q);
    }
    __syncthreads();
    if (t < 16) atomicAdd(&bnsum[t], sbn[t]);
    else if (t < 32) atomicAdd(&bnsq[t - 16], sbn[t]);
  }
}

__global__ void k_bnp(const float* __restrict__ bnsum, const float* __restrict__ bnsq,
                      const float* __restrict__ g, const float* __restrict__ bb,
                      float* __restrict__ scale, float* __restrict__ shift, float invn) {
  int c = threadIdx.x;
  if (c >= C) return;
  float mean = bnsum[c] * invn;
  float var = bnsq[c] * invn - mean * mean;
  float s = g[c] * rsqrtf(var + 1e-5f);
  scale[c] = s; shift[c] = bb[c] - mean * s;
}

// ---------------- BN + 16x16 matmul + a_s/a_d for layer 2 ----------------
__global__ __launch_bounds__(256) void k_node2(
    const float* __restrict__ outv, const float* __restrict__ scale,
    const float* __restrict__ shift, const float* __restrict__ W2,
    const float* __restrict__ asw, const float* __restrict__ adw,
    float* __restrict__ h, float* __restrict__ a_s, float* __restrict__ a_d, int n) {
  __shared__ float w2s[C * C];
  if (threadIdx.x < C * C) w2s[threadIdx.x] = W2[threadIdx.x];
  __syncthreads();
  int i = blockIdx.x * 256 + threadIdx.x;
  if (i >= n) return;
  float hn[C];
  #pragma unroll
  for (int c = 0; c < C; ++c) hn[c] = outv[(size_t)i * C + c] * scale[c] + shift[c];
  float h2[C];
  #pragma unroll
  for (int j = 0; j < C; ++j) {
    float acc = 0.f;
    #pragma unroll
    for (int c = 0; c < C; ++c) acc += hn[c] * w2s[c * C + j];
    h2[j] = acc;
  }
  float hs = 0.f, hd = 0.f;
  #pragma unroll
  for (int j = 0; j < C; ++j) { hs += h2[j] * asw[j]; hd += h2[j] * adw[j]; }
  a_s[i] = hs; a_d[i] = hd;
  float4* hp = (float4*)&h[(size_t)i * C];
  hp[0] = make_float4(h2[0], h2[1], h2[2], h2[3]);
  hp[1] = make_float4(h2[4], h2[5], h2[6], h2[7]);
  hp[2] = make_float4(h2[8], h2[9], h2[10], h2[11]);
  hp[3] = make_float4(h2[12], h2[13], h2[14], h2[15]);
}

// ---------------- graph segment offsets ----------------
__global__ void k_gstart(const int* __restrict__ batch, int* __restrict__ gs,
                         int n, int B_) {
  int g = blockIdx.x * blockDim.x + threadIdx.x;
  if (g > B_) return;
  if (g == B_) { gs[B_] = n; return; }
  int lo = 0, hi = n;
  while (lo < hi) { int mid = (lo + hi) >> 1; if (batch[mid] < g) lo = mid + 1; else hi = mid; }
  gs[g] = lo;
}

__global__ __launch_bounds__(256) void k_xe(
    const float* __restrict__ outv, const int* __restrict__ gs,
    float* __restrict__ xe, int B_) {
  int wave = blockIdx.x * 4 + (threadIdx.x >> 6);
  if (wave >= B_) return;
  int lane = threadIdx.x & 63;
  int c = lane & 15, sub = lane >> 4;
  int base = gs[wave], end = gs[wave + 1];
  float s = 0.f;
  for (int n0 = base + sub; n0 < end; n0 += 4) s += outv[(size_t)n0 * C + c];
  s += __shfl_down(s, 32);
  s += __shfl_down(s, 16);
  if (lane < 16) xe[(size_t)wave * C + c] = s / fmaxf((float)(end - base), 1.f);
}

// ---------------- D2RL tail: BN/MLP stages only (z3 out, no spills) ----------------
__global__ __launch_bounds__(512) void k_tail_z3(
    const float* __restrict__ xe_in,
    const float* __restrict__ gL1, const float* __restrict__ bL1,
    const float* __restrict__ Wl1, const float* __restrict__ bl1,
    const float* __restrict__ gL2, const float* __restrict__ bL2,
    const float* __restrict__ Wl2, const float* __restrict__ bl2,
    const float* __restrict__ gL3, const float* __restrict__ bL3,
    const float* __restrict__ Wl3, const float* __restrict__ bl3,
    float* __restrict__ z3buf, int B_) {
  __shared__ float ssum[2 * C], ssq[2 * C], sc[2 * C], sh[2 * C];
  int t = threadIdx.x;
  float invB = 1.f / (float)B_;
  float xe[C];
  #pragma unroll
  for (int c = 0; c < C; ++c) xe[c] = xe_in[(size_t)t * C + c];

  if (t < 2 * C) { ssum[t] = 0.f; ssq[t] = 0.f; }
  __syncthreads();
  #pragma unroll
  for (int c = 0; c < C; ++c) {
    float s = xe[c], q = xe[c] * xe[c];
    for (int o = 32; o > 0; o >>= 1) { s += __shfl_down(s, o); q += __shfl_down(q, o); }
    if ((t & 63) == 0) { atomicAdd(&ssum[c], s); atomicAdd(&ssq[c], q); }
  }
  __syncthreads();
  if (t < C) {
    float mean = ssum[t] * invB, var = ssq[t] * invB - mean * mean;
    float s = gL1[t] * rsqrtf(var + 1e-5f);
    sc[t] = s; sh[t] = bL1[t] - mean * s;
  }
  __syncthreads();
  float z[C];
  #pragma unroll
  for (int j = 0; j < C; ++j) {
    float acc = bl1[j];
    #pragma unroll
    for (int c = 0; c < C; ++c) acc += (xe[c] * sc[c] + sh[c]) * Wl1[c * C + j];
    z[j] = fmaxf(acc, 0.f);
  }
  __syncthreads();

  if (t < 2 * C) { ssum[t] = 0.f; ssq[t] = 0.f; }
  __syncthreads();
  #pragma unroll
  for (int c = 0; c < C; ++c) {
    float s = z[c], q = z[c] * z[c];
    for (int o = 32; o > 0; o >>= 1) { s += __shfl_down(s, o); q += __shfl_down(q, o); }
    if ((t & 63) == 0) { atomicAdd(&ssum[c], s); atomicAdd(&ssq[c], q); }
    float s2 = xe[c], q2 = xe[c] * xe[c];
    for (int o = 32; o > 0; o >>= 1) { s2 += __shfl_down(s2, o); q2 += __shfl_down(q2, o); }
    if ((t & 63) == 0) { atomicAdd(&ssum[C + c], s2); atomicAdd(&ssq[C + c], q2); }
  }
  __syncthreads();
  if (t < 2 * C) {
    float mean = ssum[t] * invB, var = ssq[t] * invB - mean * mean;
    float s = gL2[t] * rsqrtf(var + 1e-5f);
    sc[t] = s; sh[t] = bL2[t] - mean * s;
  }
  __syncthreads();
  float z2[C];
  #pragma unroll
  for (int j = 0; j < C; ++j) {
    float acc = bl2[j];
    #pragma unroll
    for (int c = 0; c < C; ++c) acc += (z[c] * sc[c] + sh[c]) * Wl2[c * C + j];
    #pragma unroll
    for (int c = 0; c < C; ++c) acc += (xe[c] * sc[C + c] + sh[C + c]) * Wl2[(C + c) * C + j];
    z2[j] = fmaxf(acc, 0.f);
  }
  __syncthreads();

  if (t < 2 * C) { ssum[t] = 0.f; ssq[t] = 0.f; }
  __syncthreads();
  #pragma unroll
  for (int c = 0; c < C; ++c) {
    float s = z2[c], q = z2[c] * z2[c];
    for (int o = 32; o > 0; o >>= 1) { s += __shfl_down(s, o); q += __shfl_down(q, o); }
    if ((t & 63) == 0) { atomicAdd(&ssum[c], s); atomicAdd(&ssq[c], q); }
    float s2 = xe[c], q2 = xe[c] * xe[c];
    for (int o = 32; o > 0; o >>= 1) { s2 += __shfl_down(s2, o); q2 += __shfl_down(q2, o); }
    if ((t & 63) == 0) { atomicAdd(&ssum[C + c], s2); atomicAdd(&ssq[C + c], q2); }
  }
  __syncthreads();
  if (t < 2 * C) {
    float mean = ssum[t] * invB, var = ssq[t] * invB - mean * mean;
    float s = gL3[t] * rsqrtf(var + 1e-5f);
    sc[t] = s; sh[t] = bL3[t] - mean * s;
  }
  __syncthreads();
  #pragma unroll
  for (int j = 0; j < C; ++j) {
    float acc = bl3[j];
    #pragma unroll
    for (int c = 0; c < C; ++c) acc += (z2[c] * sc[c] + sh[c]) * Wl3[c * C + j];
    #pragma unroll
    for (int c = 0; c < C; ++c) acc += (xe[c] * sc[C + c] + sh[C + c]) * Wl3[(C + c) * C + j];
    z3buf[(size_t)t * C + j] = fmaxf(acc, 0.f);
  }
}

// ---------------- heads: one wave per graph, lane j = output j ----------------
__global__ __launch_bounds__(256) void k_heads(
    const float* __restrict__ z3buf,
    const float* __restrict__ Wx, const float* __restrict__ bx,
    const float* __restrict__ Wy, const float* __restrict__ by,
    const float* __restrict__ Wr, const float* __restrict__ br,
    float* __restrict__ out, int B_) {
  int wv = blockIdx.x * 4 + (threadIdx.x >> 6);
  if (wv >= B_) return;
  int lane = threadIdx.x & 63;
  float z[C];
  #pragma unroll
  for (int c = 0; c < C; ++c) z[c] = z3buf[(size_t)wv * C + c];

  // x head
  float ax = bx[lane];
  #pragma unroll
  for (int c = 0; c < C; ++c) ax += z[c] * Wx[c * 64 + lane];
  float m = ax;
  #pragma unroll
  for (int o = 32; o > 0; o >>= 1) m = fmaxf(m, __shfl_xor(m, o));
  float e = __expf(ax - m);
  float s = e;
  #pragma unroll
  for (int o = 32; o > 0; o >>= 1) s += __shfl_xor(s, o);
  out[(size_t)wv * 64 + lane] = e / s;

  // y head
  float ay = by[lane];
  #pragma unroll
  for (int c = 0; c < C; ++c) ay += z[c] * Wy[c * 64 + lane];
  m = ay;
  #pragma unroll
  for (int o = 32; o > 0; o >>= 1) m = fmaxf(m, __shfl_xor(m, o));
  e = __expf(ay - m);
  s = e;
  #pragma unroll
  for (int o = 32; o > 0; o >>= 1) s += __shfl_xor(s, o);
  out[(size_t)B_ * 64 + (size_t)wv * 64 + lane] = e / s;

  // rot head (4 outputs in lanes 0..3; shfl_xor 1,2 stays within the quad)
  if (lane < 4) {
    float ar = br[lane];
    #pragma unroll
    for (int c = 0; c < C; ++c) ar += z[c] * Wr[c * 4 + lane];
    float mr = ar;
    mr = fmaxf(mr, __shfl_xor(mr, 1));
    mr = fmaxf(mr, __shfl_xor(mr, 2));
    float er = __expf(ar - mr);
    float sr = er;
    sr += __shfl_xor(sr, 1);
    sr += __shfl_xor(sr, 2);
    out[(size_t)B_ * 128 + (size_t)wv * 4 + lane] = er / sr;
  }
}

extern "C" void kernel_launch(void* const* d_in, const int* in_sizes, int n_in,
                              void* d_out, int out_size, void* d_ws, size_t ws_size,
                              hipStream_t stream) {
  const float* x     = (const float*)d_in[0];
  const int*   eidx  = (const int*)d_in[1];
  const float* eattr = (const float*)d_in[2];
  const int*   batch = (const int*)d_in[3];
  const float* W1  = (const float*)d_in[4];
  const float* We1 = (const float*)d_in[5];
  const float* as1 = (const float*)d_in[6];
  const float* ad1 = (const float*)d_in[7];
  const float* ae1 = (const float*)d_in[8];
  const float* b1  = (const float*)d_in[9];
  const float* g1  = (const float*)d_in[10];
  const float* bb1 = (const float*)d_in[11];
  const float* W2  = (const float*)d_in[12];
  const float* We2 = (const float*)d_in[13];
  const float* as2 = (const float*)d_in[14];
  const float* ad2 = (const float*)d_in[15];
  const float* ae2 = (const float*)d_in[16];
  const float* b2  = (const float*)d_in[17];
  const float* gL1 = (const float*)d_in[18];
  const float* bL1 = (const float*)d_in[19];
  const float* Wl1 = (const float*)d_in[20];
  const float* bl1 = (const float*)d_in[21];
  const float* gL2 = (const float*)d_in[22];
  const float* bL2 = (const float*)d_in[23];
  const float* Wl2 = (const float*)d_in[24];
  const float* bl2 = (const float*)d_in[25];
  const float* gL3 = (const float*)d_in[26];
  const float* bL3 = (const float*)d_in[27];
  const float* Wl3 = (const float*)d_in[28];
  const float* bl3 = (const float*)d_in[29];
  const float* Wx  = (const float*)d_in[30];
  const float* bx  = (const float*)d_in[31];
  const float* Wy  = (const float*)d_in[32];
  const float* by  = (const float*)d_in[33];
  const float* Wr  = (const float*)d_in[34];
  const float* br  = (const float*)d_in[35];

  int N = in_sizes[3];
  int E = in_sizes[2] / 2;
  int B = out_size / 132;
  int nblk = (N + 511) / 512;

  char* w = (char*)d_ws;
  size_t o = 0;
  auto alloc = [&](size_t bytes) { char* p = w + o; o += (bytes + 15) & ~15ull; return p; };
  uint2* bucket  = (uint2*)alloc((size_t)E * 8);
  int*   rank    = (int*)alloc((size_t)E * 4);
  float* h       = (float*)alloc((size_t)N * C * 4);
  float* outv    = (float*)alloc((size_t)N * C * 4);
  float* a_s     = (float*)alloc((size_t)N * 4);
  float* a_d     = (float*)alloc((size_t)N * 4);
  int*   counts  = (int*)alloc((size_t)N * 4);
  int*   offs    = (int*)alloc((size_t)(N + 4) * 4);
  int*   bsum    = (int*)alloc((size_t)(nblk + 4) * 4);
  float* bn      = (float*)alloc(64 * 4);
  float* xe      = (float*)alloc((size_t)B * C * 4);
  int*   gs      = (int*)alloc((size_t)(B + 4) * 4);
  float* z3buf   = (float*)alloc((size_t)B * C * 4);

  const int* src = eidx;
  const int* dst = eidx + E;
  int ebl = (E + 255) / 256;
  int nbl = (N + 255) / 256;

  hipMemsetAsync(counts, 0, (size_t)N * 4, stream);
  hipMemsetAsync(bn, 0, 32 * 4, stream);

  k_gemm1<<<(N + 63) / 64, 256, 0, stream>>>(x, W1, as1, ad1, h, a_s, a_d, N);
  k_hist_rank<<<ebl, 256, 0, stream>>>(dst, counts, rank, E);
  k_scan1<<<nblk, 512, 0, stream>>>(counts, bsum, N);
  k_scan2<<<1, 512, 0, stream>>>(bsum, offs, nblk, N);
  k_scan3<<<nblk, 512, 0, stream>>>(counts, bsum, offs, N);
  k_scatter<<<ebl, 256, 0, stream>>>(src, dst, (const float2*)eattr, offs, rank, bucket, E);
  k_gather<<<(N + 15) / 16, 256, 0, stream>>>(bucket, offs, a_s, a_d, h, We1, ae1, b1,
                                              outv, bn, bn + 16, 1, N);
  k_bnp<<<1, 64, 0, stream>>>(bn, bn + 16, g1, bb1, bn + 32, bn + 48, 1.f / (float)N);
  k_node2<<<nbl, 256, 0, stream>>>(outv, bn + 32, bn + 48, W2, as2, ad2, h, a_s, a_d, N);
  k_gather<<<(N + 15) / 16, 256, 0, stream>>>(bucket, offs, a_s, a_d, h, We2, ae2, b2,
                                              outv, bn, bn + 16, 0, N);
  k_gstart<<<(B + 1 + 255) / 256, 256, 0, stream>>>(batch, gs, N, B);
  k_xe<<<(B + 3) / 4, 256, 0, stream>>>(outv, gs, xe, B);
  k_tail_z3<<<1, B, 0, stream>>>(xe, gL1, bL1, Wl1, bl1, gL2, bL2, Wl2, bl2,
                                 gL3, bL3, Wl3, bl3, z3buf, B);
  k_heads<<<(B + 3) / 4, 256, 0, stream>>>(z3buf, Wx, bx, Wy, by, Wr, br,
                                           (float*)d_out, B);
}